// Round 1
// baseline (225.685 us; speedup 1.0000x reference)
//
#include <hip/hip_runtime.h>

#define DIM 512
#define BATCH 65536
#define BM 64
#define THREADS 512

typedef float f32x4 __attribute__((ext_vector_type(4)));
typedef float f32x16 __attribute__((ext_vector_type(16)));
typedef __bf16 bf16x8 __attribute__((ext_vector_type(8)));

__device__ __forceinline__ unsigned short f2bf(float f) {
    unsigned u = __float_as_uint(f);
    return (unsigned short)((u + 0x7FFFu + ((u >> 16) & 1u)) >> 16);
}

// Sb[e][d] = bf16(A[e][d] + A[d][e])  (row-major 512x512, 512 KB in d_ws)
__global__ void prep_S(const float* __restrict__ A, unsigned short* __restrict__ Sb) {
    int idx = blockIdx.x * 256 + threadIdx.x;   // 0 .. 262143
    int i = idx >> 9;
    int j = idx & 511;
    Sb[idx] = f2bf(A[idx] + A[j * DIM + i]);
}

// out[b][0:512] = p[b] + q[b] . S   ;   out[b][512:1024] = q[b]
__global__ __launch_bounds__(THREADS, 2)
void gemm_kernel(const float* __restrict__ pq,
                 const unsigned short* __restrict__ Sb,
                 float* __restrict__ out) {
    __shared__ unsigned short qs[BM * DIM];   // 64 KB, XOR-swizzled bf16 q tile
    const int b0 = blockIdx.x * BM;
    const int tid = threadIdx.x;

    // ---- Stage q tile -> LDS (bf16, swizzled) and fuse the q -> out[:,512:] copy
    #pragma unroll
    for (int i = 0; i < 16; ++i) {
        int flat = (tid + i * THREADS) * 4;   // element index in the 64x512 tile
        int r = flat >> 9;
        int c = flat & 511;
        const size_t g = (size_t)(b0 + r) * 1024 + 512 + c;
        f32x4 v = *(const f32x4*)(pq + g);
        *(f32x4*)(out + g) = v;               // q passthrough (exact fp32)
        unsigned lo = (unsigned)f2bf(v.x) | ((unsigned)f2bf(v.y) << 16);
        unsigned hi = (unsigned)f2bf(v.z) | ((unsigned)f2bf(v.w) << 16);
        int byteoff = (c * 2) ^ ((r & 15) << 4);   // swizzle 16B chunks within row
        *(uint2*)((char*)qs + r * 1024 + byteoff) = make_uint2(lo, hi);
    }
    __syncthreads();

    const int wid   = tid >> 6;
    const int lane  = tid & 63;
    const int waveM = wid >> 2;        // 0..1  (32-row slab)
    const int waveN = wid & 3;         // 0..3  (128-col panel)
    const int nbase = waveN * 128;

    const int rowA = waveM * 32 + (lane & 31);
    const int lds_row_base = rowA * 1024;           // bytes
    const int kphase = (lane >> 5) * 16;            // bytes: which 8-elem k half

    // B fragment source: S[n][k], n = nbase + nf*32 + (lane&31), k = k0 + (lane>>5)*8
    const unsigned short* Sp = Sb + (size_t)(nbase + (lane & 31)) * DIM + (lane >> 5) * 8;

    f32x16 acc0 = {}, acc1 = {}, acc2 = {}, acc3 = {};

    for (int k0 = 0; k0 < DIM; k0 += 16) {
        int byteoff = (k0 * 2 + kphase) ^ ((rowA & 15) << 4);
        bf16x8 a = *(const bf16x8*)((const char*)qs + lds_row_base + byteoff);
        bf16x8 bv0 = *(const bf16x8*)(Sp + 0 * 32 * DIM + k0);
        bf16x8 bv1 = *(const bf16x8*)(Sp + 1 * 32 * DIM + k0);
        bf16x8 bv2 = *(const bf16x8*)(Sp + 2 * 32 * DIM + k0);
        bf16x8 bv3 = *(const bf16x8*)(Sp + 3 * 32 * DIM + k0);
        acc0 = __builtin_amdgcn_mfma_f32_32x32x16_bf16(a, bv0, acc0, 0, 0, 0);
        acc1 = __builtin_amdgcn_mfma_f32_32x32x16_bf16(a, bv1, acc1, 0, 0, 0);
        acc2 = __builtin_amdgcn_mfma_f32_32x32x16_bf16(a, bv2, acc2, 0, 0, 0);
        acc3 = __builtin_amdgcn_mfma_f32_32x32x16_bf16(a, bv3, acc3, 0, 0, 0);
    }

    // ---- Epilogue: out = p + acc.  C/D layout (m74/m101): col=lane&31,
    // row = (reg&3) + 8*(reg>>2) + 4*(lane>>5)
    const int col0 = nbase + (lane & 31);
    const int rsub = 4 * (lane >> 5);
    #pragma unroll
    for (int reg = 0; reg < 16; ++reg) {
        int row = (reg & 3) + 8 * (reg >> 2) + rsub;
        size_t g = (size_t)(b0 + waveM * 32 + row) * 1024;
        out[g + col0 +  0] = pq[g + col0 +  0] + acc0[reg];
        out[g + col0 + 32] = pq[g + col0 + 32] + acc1[reg];
        out[g + col0 + 64] = pq[g + col0 + 64] + acc2[reg];
        out[g + col0 + 96] = pq[g + col0 + 96] + acc3[reg];
    }
}

extern "C" void kernel_launch(void* const* d_in, const int* in_sizes, int n_in,
                              void* d_out, int out_size, void* d_ws, size_t ws_size,
                              hipStream_t stream) {
    const float* pq = (const float*)d_in[0];
    const float* A  = (const float*)d_in[1];
    float* out = (float*)d_out;
    unsigned short* Sb = (unsigned short*)d_ws;   // 512 KB scratch

    prep_S<<<(DIM * DIM) / 256, 256, 0, stream>>>(A, Sb);
    gemm_kernel<<<BATCH / BM, THREADS, 0, stream>>>(pq, Sb, out);
}

// Round 2
// 160.180 us; speedup vs baseline: 1.4089x; 1.4089x over previous
//
#include <hip/hip_runtime.h>

#define DIM 512
#define BATCH 65536
#define BM 32
#define THREADS 512

typedef float f32x4 __attribute__((ext_vector_type(4)));
typedef float f32x16 __attribute__((ext_vector_type(16)));
typedef __bf16 bf16x8 __attribute__((ext_vector_type(8)));

__device__ __forceinline__ unsigned f2bf(float f) {
    unsigned u = __float_as_uint(f);
    return (u + 0x7FFFu + ((u >> 16) & 1u)) >> 16;
}

// Sf in MFMA-B-fragment order: Sf[((k0*16 + np)*64 + lane)*8 + j]
//   = bf16( A[n][k] + A[k][n] ),  n = np*32 + (lane&31),  k = k0*16 + (lane>>5)*8 + j
// so the gemm's B-load for fragment (np,k0) is lane-contiguous (coalesced 1 KB).
__global__ void prep_Sfrag(const float* __restrict__ A, unsigned short* __restrict__ Sf) {
    int idx = blockIdx.x * 256 + threadIdx.x;    // 0..32767 : (k0, np, lane)
    int lane = idx & 63;
    int np   = (idx >> 6) & 15;
    int k0   = idx >> 10;
    int n     = np * 32 + (lane & 31);
    int kbase = k0 * 16 + (lane >> 5) * 8;
    unsigned short tmp[8];
    #pragma unroll
    for (int j = 0; j < 8; ++j) {
        int k = kbase + j;
        tmp[j] = (unsigned short)f2bf(A[n * DIM + k] + A[k * DIM + n]);
    }
    *(uint4*)(Sf + (size_t)idx * 8) = *(const uint4*)tmp;
}

// out[b][0:512] = p[b] + q[b].S ; out[b][512:1024] = q[b]
__global__ __launch_bounds__(THREADS, 4)
void gemm_kernel(const float* __restrict__ pq,
                 const unsigned short* __restrict__ Sf,
                 float* __restrict__ out) {
    __shared__ unsigned short qs[BM * DIM];   // 32 KB, XOR-swizzled bf16 q tile
    const int b0 = blockIdx.x * BM;
    const int tid = threadIdx.x;

    // ---- Stage q tile -> LDS (bf16, swizzled); fuse q -> out[:,512:] copy
    #pragma unroll
    for (int i = 0; i < 8; ++i) {
        int flat = (tid + i * THREADS) * 4;
        int r = flat >> 9;
        int c = flat & 511;
        const size_t g = (size_t)(b0 + r) * 1024 + 512 + c;
        f32x4 v = *(const f32x4*)(pq + g);
        *(f32x4*)(out + g) = v;               // q passthrough (exact fp32)
        unsigned lo = f2bf(v.x) | (f2bf(v.y) << 16);
        unsigned hi = f2bf(v.z) | (f2bf(v.w) << 16);
        int byteoff = (c * 2) ^ ((r & 15) << 4);
        *(uint2*)((char*)qs + r * 1024 + byteoff) = make_uint2(lo, hi);
    }
    __syncthreads();

    const int wid  = tid >> 6;       // 0..7 : 64-col panel
    const int lane = tid & 63;
    const int row  = lane & 31;      // A-frag row within the 32-row slab
    const int kphase = (lane >> 5) * 16;    // bytes

    // B fragments: panels np = wid*2 + {0,1}; lane-contiguous in Sf.
    const unsigned short* Sfp = Sf + ((size_t)(wid * 2) * 64 + lane) * 8;

    f32x16 acc0 = {}, acc1 = {};
    #pragma unroll 4
    for (int k0 = 0; k0 < 32; ++k0) {
        int byteoff = (k0 * 32 + kphase) ^ ((row & 15) << 4);
        bf16x8 a   = *(const bf16x8*)((const char*)qs + row * 1024 + byteoff);
        bf16x8 bv0 = *(const bf16x8*)(Sfp + (size_t)k0 * 8192);
        bf16x8 bv1 = *(const bf16x8*)(Sfp + (size_t)k0 * 8192 + 512);
        acc0 = __builtin_amdgcn_mfma_f32_32x32x16_bf16(a, bv0, acc0, 0, 0, 0);
        acc1 = __builtin_amdgcn_mfma_f32_32x32x16_bf16(a, bv1, acc1, 0, 0, 0);
    }

    // ---- Epilogue: out = p + acc.  C/D layout: col=lane&31,
    // row = (reg&3) + 8*(reg>>2) + 4*(lane>>5)
    const int col0 = wid * 64 + row;
    const int rsub = 4 * (lane >> 5);
    #pragma unroll
    for (int reg = 0; reg < 16; ++reg) {
        int r = (reg & 3) + 8 * (reg >> 2) + rsub;
        size_t g = (size_t)(b0 + r) * 1024;
        out[g + col0 +  0] = pq[g + col0 +  0] + acc0[reg];
        out[g + col0 + 32] = pq[g + col0 + 32] + acc1[reg];
    }
}

extern "C" void kernel_launch(void* const* d_in, const int* in_sizes, int n_in,
                              void* d_out, int out_size, void* d_ws, size_t ws_size,
                              hipStream_t stream) {
    const float* pq = (const float*)d_in[0];
    const float* A  = (const float*)d_in[1];
    float* out = (float*)d_out;
    unsigned short* Sf = (unsigned short*)d_ws;   // 512 KB fragment-ordered S

    prep_Sfrag<<<128, 256, 0, stream>>>(A, Sf);
    gemm_kernel<<<BATCH / BM, THREADS, 0, stream>>>(pq, Sf, out);
}